// Round 6
// baseline (95.350 us; speedup 1.0000x reference)
//
#include <hip/hip_runtime.h>

// ---------------------------------------------------------------------------
// TreeEncoder fused MFMA kernel, round 6.
//   Rounds 4/5 both stuck at ~71.5 us with ALL pipes <45% busy -> the limiter
//   is the per-t barrier schedule (32 block-wide barriers), not a pipe.
//   This round: ZERO inner barriers.
//     - B-fragments read directly from L2 per wave (852 MB L2 ~ 24.7 us of
//       service time, overlappable; LDS staging was saving BW we don't need).
//     - register double-buffer: t+1's 12 fragments are loaded AFTER t's
//       MFMAs, so ~300cy L2 latency hides under t's ~600cy activation phase.
//     - hbuf is wave-private (DS in-order per wave) -> no syncs needed.
//     - LDS 36.9 KB -> 4 blocks/CU; __launch_bounds__(256,4) caps VGPR at 128
//       -> 16 waves/CU; grid 1024 = exactly 4 blocks/CU resident, no tail.
//     - biases pre-combined + exp2-prescaled into ws by prep.
// ---------------------------------------------------------------------------

typedef short bf16x8 __attribute__((ext_vector_type(8)));
typedef float f32x4  __attribute__((ext_vector_type(4)));

#define MFMA16(a, b, c) __builtin_amdgcn_mfma_f32_16x16x32_bf16((a), (b), (c), 0, 0, 0)

#define NEG_L2E (-1.44269504088896f)
#define TWO_L2E (2.88539008177793f)

__device__ __forceinline__ unsigned short f2bf(float f) {
    return (unsigned short)((__float_as_uint(f) + 0x8000u) >> 16);
}
__device__ __forceinline__ float frcp(float x)  { return __builtin_amdgcn_rcpf(x); }
__device__ __forceinline__ float fexp2(float x) { return __builtin_amdgcn_exp2f(x); }

// ---------------------------------------------------------------------------
// Prep: weights -> MFMA B-fragment bf16 layout in ws, with exp2 prescale;
// plus combined scaled biases.
//   B-frag (16x16x32): lane l holds B[k][n], n = 16*t + (l&15),
//   k = 32*kk + 8*(l>>4) + e.  1KB blocks: [block][lane][16B].
//   ws map (bytes):
//     [0, 16384)        emb_W: block = t*2 + kk          (unscaled)
//     [16384, 212992)   gates: block = (layer*8+t)*12 + gate*4 + kk
//         gate 0/1 (Wi,Wo): * -log2e    gate 2 (Wc): * 2*log2e
//     [212992, 216064)  biases: float[2][3][128], same scaling, bW+bU combined
// ---------------------------------------------------------------------------
__global__ void prep_frags(const float* __restrict__ embW,
                           const float* __restrict__ Wi,
                           const float* __restrict__ Wo,
                           const float* __restrict__ Wc,
                           const float* __restrict__ bWi, const float* __restrict__ bUi,
                           const float* __restrict__ bWo, const float* __restrict__ bUo,
                           const float* __restrict__ bWc, const float* __restrict__ bUc,
                           char* __restrict__ ws) {
    int fb = blockIdx.x;          // 0..208
    int l  = threadIdx.x;         // 0..63

    if (fb == 208) {              // combined scaled biases: [layer][gate][128]
        float* bias = reinterpret_cast<float*>(ws + 212992);
#pragma unroll
        for (int j = 0; j < 12; ++j) {
            int v = j * 64 + l;                 // 0..767
            int layer = v / 384;
            int r = v % 384;
            int gate = r >> 7;
            int c = r & 127;
            int idx = layer * 128 + c;
            float x;
            if (gate == 0)      x = NEG_L2E * (bWi[idx] + bUi[idx]);
            else if (gate == 1) x = NEG_L2E * (bWo[idx] + bUo[idx]);
            else                x = TWO_L2E * (bWc[idx] + bUc[idx]);
            bias[v] = x;
        }
        return;
    }

    int g  = l >> 4, c0 = l & 15;
    const float* src;
    int t, kk;
    size_t dst;
    float scale;
    if (fb < 16) {
        t = fb >> 1; kk = fb & 1;
        src = embW;                                   // [64][128]
        dst = (size_t)fb * 1024;
        scale = 1.0f;
    } else {
        int r = fb - 16;                              // (layer*8+t)*12+gate*4+kk
        int layer = r / 96;
        int r2 = r % 96;
        t = r2 / 12;
        int r3 = r2 % 12;
        int gate = r3 >> 2;
        kk = r3 & 3;
        const float* Ws[3] = {Wi, Wo, Wc};
        src = Ws[gate] + (size_t)layer * 128 * 128;   // [128][128]
        dst = 16384 + (size_t)r * 1024;
        scale = (gate == 2) ? TWO_L2E : NEG_L2E;
    }

    bf16x8 v;
#pragma unroll
    for (int e = 0; e < 8; ++e) {
        int k   = kk * 32 + g * 8 + e;
        int col = t * 16 + c0;
        v[e] = (short)f2bf(scale * src[(size_t)k * 128 + col]);
    }
    *reinterpret_cast<bf16x8*>(ws + dst + (size_t)l * 16) = v;
}

// ---------------------------------------------------------------------------
// One t-step of a layer: MFMA (CUR frags) -> issue NXT loads -> activations.
// Fully inlined, all indices compile-time -> arrays stay in registers.
// ---------------------------------------------------------------------------
template<int T, int LAYER>
__device__ __forceinline__ void t_step(
        bf16x8 (&CUR)[12], bf16x8 (&NXT)[12],
        const bf16x8 (&A)[2][4],
        const char* __restrict__ fW,
        const float* __restrict__ bias,
        int l, int c0, int g,
        float (&msum)[8],
        unsigned short (* __restrict__ hb)[136]) {

    const int c = T * 16 + c0;
    const float Bi = bias[c];
    const float Bo = bias[128 + c];
    const float Bc = bias[256 + c];

    const f32x4 z4 = {0.f, 0.f, 0.f, 0.f};
    f32x4 ai[2] = {z4, z4}, ao[2] = {z4, z4}, ac[2] = {z4, z4};
#pragma unroll
    for (int kk = 0; kk < 4; ++kk) {
#pragma unroll
        for (int mi = 0; mi < 2; ++mi) {
            ai[mi] = MFMA16(A[mi][kk], CUR[kk],     ai[mi]);
            ao[mi] = MFMA16(A[mi][kk], CUR[4 + kk], ao[mi]);
            ac[mi] = MFMA16(A[mi][kk], CUR[8 + kk], ac[mi]);
        }
    }

    // issue-early for t+1: L2 latency hides under the activation phase below
    if (T < 7) {
        const char* src = fW + (size_t)(T + 1) * 12288 + (size_t)l * 16;
#pragma unroll
        for (int i = 0; i < 12; ++i)
            NXT[i] = *reinterpret_cast<const bf16x8*>(src + (size_t)i * 1024);
    }

#pragma unroll
    for (int mi = 0; mi < 2; ++mi) {
#pragma unroll
        for (int r = 0; r < 4; ++r) {
            // logits already scaled: xi' = -log2e*xi, xc' = 2log2e*xc
            float ei = fexp2(ai[mi][r] + Bi);                 // e^-xi
            float eo = fexp2(ao[mi][r] + Bo);                 // e^-xo
            float xc = fminf(ac[mi][r] + Bc, 126.0f);
            float u  = fexp2(xc);                             // e^{2 xc}
            float cc = (u - 1.0f) * frcp((1.0f + ei) * (u + 1.0f));  // sig(i)*tanh(c~)
            float u2   = cc * cc;                             // Pade[5/4] tanh, |cc|<1
            float numx = cc * ((u2 + 105.0f) * u2 + 945.0f);
            float den  = ((15.0f * u2 + 420.0f) * u2 + 945.0f) * (1.0f + eo);
            float h    = numx * frcp(den);
            if (LAYER == 1) msum[T] += h;
            else hb[mi * 16 + g * 4 + r][c] = f2bf(h);
        }
    }
}

// ---------------------------------------------------------------------------
// Main fused kernel: 1024 blocks x 256 threads; each wave owns 32 rows.
// NO block-wide barriers until the final reduce.
// ---------------------------------------------------------------------------
__global__ __launch_bounds__(256, 4) void tree_enc(
        const float* __restrict__ X,       // [131072][64]
        const float* __restrict__ emb_b,   // [128]
        const char*  __restrict__ frags,   // ws
        float* __restrict__ out) {         // [256][128]

    __shared__ __align__(16) unsigned short hbuf[4][32][136];   // 34816 B
    __shared__ float redbuf[4][128];                            //  2048 B

    const int tid = threadIdx.x;
    const int w   = tid >> 6;
    const int l   = tid & 63;
    const int g   = l >> 4;
    const int c0  = l & 15;
    const int rowbase = blockIdx.x * 128 + w * 32;
    const int b  = blockIdx.x >> 2;       // 4 blocks per batch

    unsigned short (* __restrict__ hb)[136] = hbuf[w];
    const float* biasf = reinterpret_cast<const float*>(frags + 212992);

    // ---------------- embedding: h0 = X @ embW + emb_b ----------------
    {
        bf16x8 afr[2][2];
#pragma unroll
        for (int mi = 0; mi < 2; ++mi) {
#pragma unroll
            for (int kk = 0; kk < 2; ++kk) {
                int row = rowbase + mi * 16 + c0;
                const float4* p = reinterpret_cast<const float4*>(
                        X + (size_t)row * 64 + kk * 32 + g * 8);
                float4 v0 = p[0], v1 = p[1];
                bf16x8 a;
                a[0] = (short)f2bf(v0.x); a[1] = (short)f2bf(v0.y);
                a[2] = (short)f2bf(v0.z); a[3] = (short)f2bf(v0.w);
                a[4] = (short)f2bf(v1.x); a[5] = (short)f2bf(v1.y);
                a[6] = (short)f2bf(v1.z); a[7] = (short)f2bf(v1.w);
                afr[mi][kk] = a;
            }
        }
        const f32x4 z4 = {0.f, 0.f, 0.f, 0.f};
#pragma unroll
        for (int t = 0; t < 8; ++t) {
            f32x4 acc[2] = {z4, z4};
#pragma unroll
            for (int kk = 0; kk < 2; ++kk) {
                bf16x8 bf = *reinterpret_cast<const bf16x8*>(
                        frags + ((size_t)(t * 2 + kk) * 64 + l) * 16);
#pragma unroll
                for (int mi = 0; mi < 2; ++mi)
                    acc[mi] = MFMA16(afr[mi][kk], bf, acc[mi]);
            }
            float bias = emb_b[t * 16 + c0];
#pragma unroll
            for (int mi = 0; mi < 2; ++mi)
#pragma unroll
                for (int r = 0; r < 4; ++r)
                    hb[mi * 16 + g * 4 + r][t * 16 + c0] =
                        f2bf(acc[mi][r] + bias);   // C: col=l&15, row=4*(l>>4)+r
        }
    }

    // ---------------- 2 TreeLSTM layers (no barriers) ----------------
    float msum[8];
#pragma unroll
    for (int t = 0; t < 8; ++t) msum[t] = 0.f;

#define RUN_LAYER(L) do {                                                     \
        const char* fW = frags + 16384 + (size_t)(L) * 98304;                 \
        const float* bias = biasf + (L) * 384;                                \
        bf16x8 A[2][4];                                                       \
        _Pragma("unroll") for (int mi = 0; mi < 2; ++mi)                      \
        _Pragma("unroll") for (int kk = 0; kk < 4; ++kk)                      \
            A[mi][kk] = *reinterpret_cast<const bf16x8*>(                     \
                    &hb[mi * 16 + c0][kk * 32 + g * 8]);                      \
        bf16x8 bufA[12], bufB[12];                                            \
        { const char* s0 = fW + (size_t)l * 16;                               \
          _Pragma("unroll") for (int i = 0; i < 12; ++i)                      \
              bufA[i] = *reinterpret_cast<const bf16x8*>(s0 + (size_t)i * 1024); } \
        t_step<0, L>(bufA, bufB, A, fW, bias, l, c0, g, msum, hb);            \
        t_step<1, L>(bufB, bufA, A, fW, bias, l, c0, g, msum, hb);            \
        t_step<2, L>(bufA, bufB, A, fW, bias, l, c0, g, msum, hb);            \
        t_step<3, L>(bufB, bufA, A, fW, bias, l, c0, g, msum, hb);            \
        t_step<4, L>(bufA, bufB, A, fW, bias, l, c0, g, msum, hb);            \
        t_step<5, L>(bufB, bufA, A, fW, bias, l, c0, g, msum, hb);            \
        t_step<6, L>(bufA, bufB, A, fW, bias, l, c0, g, msum, hb);            \
        t_step<7, L>(bufB, bufA, A, fW, bias, l, c0, g, msum, hb);            \
    } while (0)

    RUN_LAYER(0);
    RUN_LAYER(1);
#undef RUN_LAYER

    // ---------------- mean over nodes (single barrier) ----------------
#pragma unroll
    for (int t = 0; t < 8; ++t) {
        float v = msum[t];
        v += __shfl_xor(v, 16);
        v += __shfl_xor(v, 32);
        if (g == 0) redbuf[w][t * 16 + c0] = v;
    }
    __syncthreads();
    if (tid < 128) {
        float s = redbuf[0][tid] + redbuf[1][tid] + redbuf[2][tid] + redbuf[3][tid];
        atomicAdd(&out[b * 128 + tid], s * (1.0f / 512.0f));
    }
}

// ---------------------------------------------------------------------------
extern "C" void kernel_launch(void* const* d_in, const int* in_sizes, int n_in,
                              void* d_out, int out_size, void* d_ws, size_t ws_size,
                              hipStream_t stream) {
    const float* X    = (const float*)d_in[0];
    const float* embW = (const float*)d_in[1];
    const float* embb = (const float*)d_in[2];
    const float* Wi   = (const float*)d_in[3];
    const float* Wo   = (const float*)d_in[4];
    const float* Wc   = (const float*)d_in[5];
    const float* bWi  = (const float*)d_in[6];
    const float* bUi  = (const float*)d_in[7];
    const float* bWo  = (const float*)d_in[8];
    const float* bUo  = (const float*)d_in[9];
    const float* bWc  = (const float*)d_in[10];
    const float* bUc  = (const float*)d_in[11];
    float* out = (float*)d_out;
    char*  ws  = (char*)d_ws;

    hipMemsetAsync(d_out, 0, (size_t)out_size * sizeof(float), stream);
    prep_frags<<<209, 64, 0, stream>>>(embW, Wi, Wo, Wc,
                                       bWi, bUi, bWo, bUo, bWc, bUc, ws);
    tree_enc<<<1024, 256, 0, stream>>>(X, embb, (const char*)ws, out);
}

// Round 7
// 83.543 us; speedup vs baseline: 1.1413x; 1.1413x over previous
//
#include <hip/hip_runtime.h>

// ---------------------------------------------------------------------------
// TreeEncoder fused MFMA kernel, round 7.
//   Round 6 (zero-barrier, reg-double-buffered) was correct but
//   __launch_bounds__(256,4) clamped VGPR to 64 -> 148 MB scratch spills.
//   Round 7 = round 6 with the cap removed (plain launch_bounds(256)):
//   compiler free to allocate ~165 VGPR (rounds 1/4/5 precedent: no spill).
//   LDS 36.9 KB -> 3-4 blocks/CU; zero inner barriers; waves drift freely so
//   VALU/TRANS (the dominant pipe, ~31.6 us busy) stays fed while L2
//   fragment streaming (~25 us) and MFMA (~10.7 us) overlap underneath.
// ---------------------------------------------------------------------------

typedef short bf16x8 __attribute__((ext_vector_type(8)));
typedef float f32x4  __attribute__((ext_vector_type(4)));

#define MFMA16(a, b, c) __builtin_amdgcn_mfma_f32_16x16x32_bf16((a), (b), (c), 0, 0, 0)

#define NEG_L2E (-1.44269504088896f)
#define TWO_L2E (2.88539008177793f)

__device__ __forceinline__ unsigned short f2bf(float f) {
    return (unsigned short)((__float_as_uint(f) + 0x8000u) >> 16);
}
__device__ __forceinline__ float frcp(float x)  { return __builtin_amdgcn_rcpf(x); }
__device__ __forceinline__ float fexp2(float x) { return __builtin_amdgcn_exp2f(x); }

// ---------------------------------------------------------------------------
// Prep: weights -> MFMA B-fragment bf16 layout in ws, with exp2 prescale;
// plus combined scaled biases.
//   B-frag (16x16x32): lane l holds B[k][n], n = 16*t + (l&15),
//   k = 32*kk + 8*(l>>4) + e.  1KB blocks: [block][lane][16B].
//   ws map (bytes):
//     [0, 16384)        emb_W: block = t*2 + kk          (unscaled)
//     [16384, 212992)   gates: block = (layer*8+t)*12 + gate*4 + kk
//         gate 0/1 (Wi,Wo): * -log2e    gate 2 (Wc): * 2*log2e
//     [212992, 216064)  biases: float[2][3][128], same scaling, bW+bU combined
// ---------------------------------------------------------------------------
__global__ void prep_frags(const float* __restrict__ embW,
                           const float* __restrict__ Wi,
                           const float* __restrict__ Wo,
                           const float* __restrict__ Wc,
                           const float* __restrict__ bWi, const float* __restrict__ bUi,
                           const float* __restrict__ bWo, const float* __restrict__ bUo,
                           const float* __restrict__ bWc, const float* __restrict__ bUc,
                           char* __restrict__ ws) {
    int fb = blockIdx.x;          // 0..208
    int l  = threadIdx.x;         // 0..63

    if (fb == 208) {              // combined scaled biases: [layer][gate][128]
        float* bias = reinterpret_cast<float*>(ws + 212992);
#pragma unroll
        for (int j = 0; j < 12; ++j) {
            int v = j * 64 + l;                 // 0..767
            int layer = v / 384;
            int r = v % 384;
            int gate = r >> 7;
            int c = r & 127;
            int idx = layer * 128 + c;
            float x;
            if (gate == 0)      x = NEG_L2E * (bWi[idx] + bUi[idx]);
            else if (gate == 1) x = NEG_L2E * (bWo[idx] + bUo[idx]);
            else                x = TWO_L2E * (bWc[idx] + bUc[idx]);
            bias[v] = x;
        }
        return;
    }

    int g  = l >> 4, c0 = l & 15;
    const float* src;
    int t, kk;
    size_t dst;
    float scale;
    if (fb < 16) {
        t = fb >> 1; kk = fb & 1;
        src = embW;                                   // [64][128]
        dst = (size_t)fb * 1024;
        scale = 1.0f;
    } else {
        int r = fb - 16;                              // (layer*8+t)*12+gate*4+kk
        int layer = r / 96;
        int r2 = r % 96;
        t = r2 / 12;
        int r3 = r2 % 12;
        int gate = r3 >> 2;
        kk = r3 & 3;
        const float* Ws[3] = {Wi, Wo, Wc};
        src = Ws[gate] + (size_t)layer * 128 * 128;   // [128][128]
        dst = 16384 + (size_t)r * 1024;
        scale = (gate == 2) ? TWO_L2E : NEG_L2E;
    }

    bf16x8 v;
#pragma unroll
    for (int e = 0; e < 8; ++e) {
        int k   = kk * 32 + g * 8 + e;
        int col = t * 16 + c0;
        v[e] = (short)f2bf(scale * src[(size_t)k * 128 + col]);
    }
    *reinterpret_cast<bf16x8*>(ws + dst + (size_t)l * 16) = v;
}

// ---------------------------------------------------------------------------
// One t-step of a layer: MFMA (CUR frags) -> issue NXT loads -> activations.
// Fully inlined, all indices compile-time -> arrays stay in registers.
// ---------------------------------------------------------------------------
template<int T, int LAYER>
__device__ __forceinline__ void t_step(
        bf16x8 (&CUR)[12], bf16x8 (&NXT)[12],
        const bf16x8 (&A)[2][4],
        const char* __restrict__ fW,
        const float* __restrict__ bias,
        int l, int c0, int g,
        float (&msum)[8],
        unsigned short (* __restrict__ hb)[136]) {

    const int c = T * 16 + c0;
    const float Bi = bias[c];
    const float Bo = bias[128 + c];
    const float Bc = bias[256 + c];

    const f32x4 z4 = {0.f, 0.f, 0.f, 0.f};
    f32x4 ai[2] = {z4, z4}, ao[2] = {z4, z4}, ac[2] = {z4, z4};
#pragma unroll
    for (int kk = 0; kk < 4; ++kk) {
#pragma unroll
        for (int mi = 0; mi < 2; ++mi) {
            ai[mi] = MFMA16(A[mi][kk], CUR[kk],     ai[mi]);
            ao[mi] = MFMA16(A[mi][kk], CUR[4 + kk], ao[mi]);
            ac[mi] = MFMA16(A[mi][kk], CUR[8 + kk], ac[mi]);
        }
    }

    // issue-early for t+1: L2 latency hides under the activation phase below
    if (T < 7) {
        const char* src = fW + (size_t)(T + 1) * 12288 + (size_t)l * 16;
#pragma unroll
        for (int i = 0; i < 12; ++i)
            NXT[i] = *reinterpret_cast<const bf16x8*>(src + (size_t)i * 1024);
    }

#pragma unroll
    for (int mi = 0; mi < 2; ++mi) {
#pragma unroll
        for (int r = 0; r < 4; ++r) {
            // logits already scaled: xi' = -log2e*xi, xc' = 2log2e*xc
            float ei = fexp2(ai[mi][r] + Bi);                 // e^-xi
            float eo = fexp2(ao[mi][r] + Bo);                 // e^-xo
            float xc = fminf(ac[mi][r] + Bc, 126.0f);
            float u  = fexp2(xc);                             // e^{2 xc}
            float cc = (u - 1.0f) * frcp((1.0f + ei) * (u + 1.0f));  // sig(i)*tanh(c~)
            float u2   = cc * cc;                             // Pade[5/4] tanh, |cc|<1
            float numx = cc * ((u2 + 105.0f) * u2 + 945.0f);
            float den  = ((15.0f * u2 + 420.0f) * u2 + 945.0f) * (1.0f + eo);
            float h    = numx * frcp(den);
            if (LAYER == 1) msum[T] += h;
            else hb[mi * 16 + g * 4 + r][c] = f2bf(h);
        }
    }
}

// ---------------------------------------------------------------------------
// Main fused kernel: 1024 blocks x 256 threads; each wave owns 32 rows.
// NO block-wide barriers until the final reduce.
// ---------------------------------------------------------------------------
__global__ __launch_bounds__(256) void tree_enc(
        const float* __restrict__ X,       // [131072][64]
        const float* __restrict__ emb_b,   // [128]
        const char*  __restrict__ frags,   // ws
        float* __restrict__ out) {         // [256][128]

    __shared__ __align__(16) unsigned short hbuf[4][32][136];   // 34816 B
    __shared__ float redbuf[4][128];                            //  2048 B

    const int tid = threadIdx.x;
    const int w   = tid >> 6;
    const int l   = tid & 63;
    const int g   = l >> 4;
    const int c0  = l & 15;
    const int rowbase = blockIdx.x * 128 + w * 32;
    const int b  = blockIdx.x >> 2;       // 4 blocks per batch

    unsigned short (* __restrict__ hb)[136] = hbuf[w];
    const float* biasf = reinterpret_cast<const float*>(frags + 212992);

    // ---------------- embedding: h0 = X @ embW + emb_b ----------------
    {
        bf16x8 afr[2][2];
#pragma unroll
        for (int mi = 0; mi < 2; ++mi) {
#pragma unroll
            for (int kk = 0; kk < 2; ++kk) {
                int row = rowbase + mi * 16 + c0;
                const float4* p = reinterpret_cast<const float4*>(
                        X + (size_t)row * 64 + kk * 32 + g * 8);
                float4 v0 = p[0], v1 = p[1];
                bf16x8 a;
                a[0] = (short)f2bf(v0.x); a[1] = (short)f2bf(v0.y);
                a[2] = (short)f2bf(v0.z); a[3] = (short)f2bf(v0.w);
                a[4] = (short)f2bf(v1.x); a[5] = (short)f2bf(v1.y);
                a[6] = (short)f2bf(v1.z); a[7] = (short)f2bf(v1.w);
                afr[mi][kk] = a;
            }
        }
        const f32x4 z4 = {0.f, 0.f, 0.f, 0.f};
#pragma unroll
        for (int t = 0; t < 8; ++t) {
            f32x4 acc[2] = {z4, z4};
#pragma unroll
            for (int kk = 0; kk < 2; ++kk) {
                bf16x8 bf = *reinterpret_cast<const bf16x8*>(
                        frags + ((size_t)(t * 2 + kk) * 64 + l) * 16);
#pragma unroll
                for (int mi = 0; mi < 2; ++mi)
                    acc[mi] = MFMA16(afr[mi][kk], bf, acc[mi]);
            }
            float bias = emb_b[t * 16 + c0];
#pragma unroll
            for (int mi = 0; mi < 2; ++mi)
#pragma unroll
                for (int r = 0; r < 4; ++r)
                    hb[mi * 16 + g * 4 + r][t * 16 + c0] =
                        f2bf(acc[mi][r] + bias);   // C: col=l&15, row=4*(l>>4)+r
        }
    }

    // ---------------- 2 TreeLSTM layers (no barriers) ----------------
    float msum[8];
#pragma unroll
    for (int t = 0; t < 8; ++t) msum[t] = 0.f;

#define RUN_LAYER(L) do {                                                     \
        const char* fW = frags + 16384 + (size_t)(L) * 98304;                 \
        const float* bias = biasf + (L) * 384;                                \
        bf16x8 A[2][4];                                                       \
        _Pragma("unroll") for (int mi = 0; mi < 2; ++mi)                      \
        _Pragma("unroll") for (int kk = 0; kk < 4; ++kk)                      \
            A[mi][kk] = *reinterpret_cast<const bf16x8*>(                     \
                    &hb[mi * 16 + c0][kk * 32 + g * 8]);                      \
        bf16x8 bufA[12], bufB[12];                                            \
        { const char* s0 = fW + (size_t)l * 16;                               \
          _Pragma("unroll") for (int i = 0; i < 12; ++i)                      \
              bufA[i] = *reinterpret_cast<const bf16x8*>(s0 + (size_t)i * 1024); } \
        t_step<0, L>(bufA, bufB, A, fW, bias, l, c0, g, msum, hb);            \
        t_step<1, L>(bufB, bufA, A, fW, bias, l, c0, g, msum, hb);            \
        t_step<2, L>(bufA, bufB, A, fW, bias, l, c0, g, msum, hb);            \
        t_step<3, L>(bufB, bufA, A, fW, bias, l, c0, g, msum, hb);            \
        t_step<4, L>(bufA, bufB, A, fW, bias, l, c0, g, msum, hb);            \
        t_step<5, L>(bufB, bufA, A, fW, bias, l, c0, g, msum, hb);            \
        t_step<6, L>(bufA, bufB, A, fW, bias, l, c0, g, msum, hb);            \
        t_step<7, L>(bufB, bufA, A, fW, bias, l, c0, g, msum, hb);            \
    } while (0)

    RUN_LAYER(0);
    RUN_LAYER(1);
#undef RUN_LAYER

    // ---------------- mean over nodes (single barrier) ----------------
#pragma unroll
    for (int t = 0; t < 8; ++t) {
        float v = msum[t];
        v += __shfl_xor(v, 16);
        v += __shfl_xor(v, 32);
        if (g == 0) redbuf[w][t * 16 + c0] = v;
    }
    __syncthreads();
    if (tid < 128) {
        float s = redbuf[0][tid] + redbuf[1][tid] + redbuf[2][tid] + redbuf[3][tid];
        atomicAdd(&out[b * 128 + tid], s * (1.0f / 512.0f));
    }
}

// ---------------------------------------------------------------------------
extern "C" void kernel_launch(void* const* d_in, const int* in_sizes, int n_in,
                              void* d_out, int out_size, void* d_ws, size_t ws_size,
                              hipStream_t stream) {
    const float* X    = (const float*)d_in[0];
    const float* embW = (const float*)d_in[1];
    const float* embb = (const float*)d_in[2];
    const float* Wi   = (const float*)d_in[3];
    const float* Wo   = (const float*)d_in[4];
    const float* Wc   = (const float*)d_in[5];
    const float* bWi  = (const float*)d_in[6];
    const float* bUi  = (const float*)d_in[7];
    const float* bWo  = (const float*)d_in[8];
    const float* bUo  = (const float*)d_in[9];
    const float* bWc  = (const float*)d_in[10];
    const float* bUc  = (const float*)d_in[11];
    float* out = (float*)d_out;
    char*  ws  = (char*)d_ws;

    hipMemsetAsync(d_out, 0, (size_t)out_size * sizeof(float), stream);
    prep_frags<<<209, 64, 0, stream>>>(embW, Wi, Wo, Wc,
                                       bWi, bUi, bWo, bUo, bWc, bUc, ws);
    tree_enc<<<1024, 256, 0, stream>>>(X, embb, (const char*)ws, out);
}

// Round 8
// 66.764 us; speedup vs baseline: 1.4282x; 1.2513x over previous
//
#include <hip/hip_runtime.h>

// ---------------------------------------------------------------------------
// TreeEncoder fused MFMA kernel, round 8.
//   Round 7 (zero-barrier, reg-DOUBLE-buffer) hit 83.5us with VGPR=148 ->
//   only 3 waves/SIMD (12 waves/CU). All pipes <45% busy => latency-bound,
//   occupancy-limited by VGPR alone (LDS 36.9KB allows 4 blocks/CU).
//   Round 8: single 12-fragment register buffer with WAR reuse (loads for
//   t+1 issue after t's MFMAs consumed the buffer; activation phase ~700cy
//   still hides L2 latency) + exact VGPR cap via amdgpu_num_vgpr(128)
//   (NOT the waves-per-EU heuristic that over-squeezed in rounds 2/6).
//   Target: 4 waves/SIMD, 16 waves/CU.
// ---------------------------------------------------------------------------

typedef short bf16x8 __attribute__((ext_vector_type(8)));
typedef float f32x4  __attribute__((ext_vector_type(4)));

#define MFMA16(a, b, c) __builtin_amdgcn_mfma_f32_16x16x32_bf16((a), (b), (c), 0, 0, 0)

#define NEG_L2E (-1.44269504088896f)
#define TWO_L2E (2.88539008177793f)

__device__ __forceinline__ unsigned short f2bf(float f) {
    return (unsigned short)((__float_as_uint(f) + 0x8000u) >> 16);
}
__device__ __forceinline__ float frcp(float x)  { return __builtin_amdgcn_rcpf(x); }
__device__ __forceinline__ float fexp2(float x) { return __builtin_amdgcn_exp2f(x); }

// ---------------------------------------------------------------------------
// Prep: weights -> MFMA B-fragment bf16 layout in ws, with exp2 prescale;
// plus combined scaled biases.
//   B-frag (16x16x32): lane l holds B[k][n], n = 16*t + (l&15),
//   k = 32*kk + 8*(l>>4) + e.  1KB blocks: [block][lane][16B].
//   ws map (bytes):
//     [0, 16384)        emb_W: block = t*2 + kk          (unscaled)
//     [16384, 212992)   gates: block = (layer*8+t)*12 + gate*4 + kk
//         gate 0/1 (Wi,Wo): * -log2e    gate 2 (Wc): * 2*log2e
//     [212992, 216064)  biases: float[2][3][128], same scaling, bW+bU combined
// ---------------------------------------------------------------------------
__global__ void prep_frags(const float* __restrict__ embW,
                           const float* __restrict__ Wi,
                           const float* __restrict__ Wo,
                           const float* __restrict__ Wc,
                           const float* __restrict__ bWi, const float* __restrict__ bUi,
                           const float* __restrict__ bWo, const float* __restrict__ bUo,
                           const float* __restrict__ bWc, const float* __restrict__ bUc,
                           char* __restrict__ ws) {
    int fb = blockIdx.x;          // 0..208
    int l  = threadIdx.x;         // 0..63

    if (fb == 208) {              // combined scaled biases: [layer][gate][128]
        float* bias = reinterpret_cast<float*>(ws + 212992);
#pragma unroll
        for (int j = 0; j < 12; ++j) {
            int v = j * 64 + l;                 // 0..767
            int layer = v / 384;
            int r = v % 384;
            int gate = r >> 7;
            int c = r & 127;
            int idx = layer * 128 + c;
            float x;
            if (gate == 0)      x = NEG_L2E * (bWi[idx] + bUi[idx]);
            else if (gate == 1) x = NEG_L2E * (bWo[idx] + bUo[idx]);
            else                x = TWO_L2E * (bWc[idx] + bUc[idx]);
            bias[v] = x;
        }
        return;
    }

    int g  = l >> 4, c0 = l & 15;
    const float* src;
    int t, kk;
    size_t dst;
    float scale;
    if (fb < 16) {
        t = fb >> 1; kk = fb & 1;
        src = embW;                                   // [64][128]
        dst = (size_t)fb * 1024;
        scale = 1.0f;
    } else {
        int r = fb - 16;                              // (layer*8+t)*12+gate*4+kk
        int layer = r / 96;
        int r2 = r % 96;
        t = r2 / 12;
        int r3 = r2 % 12;
        int gate = r3 >> 2;
        kk = r3 & 3;
        const float* Ws[3] = {Wi, Wo, Wc};
        src = Ws[gate] + (size_t)layer * 128 * 128;   // [128][128]
        dst = 16384 + (size_t)r * 1024;
        scale = (gate == 2) ? TWO_L2E : NEG_L2E;
    }

    bf16x8 v;
#pragma unroll
    for (int e = 0; e < 8; ++e) {
        int k   = kk * 32 + g * 8 + e;
        int col = t * 16 + c0;
        v[e] = (short)f2bf(scale * src[(size_t)k * 128 + col]);
    }
    *reinterpret_cast<bf16x8*>(ws + dst + (size_t)l * 16) = v;
}

// ---------------------------------------------------------------------------
// One t-step: MFMA (BUF frags) -> reload BUF for t+1 (WAR reuse: the loads
// issue after the MFMAs consumed the old values, so one 48-VGPR buffer
// serves all t) -> activations.
// ---------------------------------------------------------------------------
template<int T, int LAYER>
__device__ __forceinline__ void t_step(
        bf16x8 (&BUF)[12],
        const bf16x8 (&A)[2][4],
        const char* __restrict__ fW,
        const float* __restrict__ bias,
        int l, int c0, int g,
        float (&msum)[8],
        unsigned short (* __restrict__ hb)[136]) {

    const int c = T * 16 + c0;
    const float Bi = bias[c];
    const float Bo = bias[128 + c];
    const float Bc = bias[256 + c];

    const f32x4 z4 = {0.f, 0.f, 0.f, 0.f};
    f32x4 ai[2] = {z4, z4}, ao[2] = {z4, z4}, ac[2] = {z4, z4};
#pragma unroll
    for (int kk = 0; kk < 4; ++kk) {
#pragma unroll
        for (int mi = 0; mi < 2; ++mi) {
            ai[mi] = MFMA16(A[mi][kk], BUF[kk],     ai[mi]);
            ao[mi] = MFMA16(A[mi][kk], BUF[4 + kk], ao[mi]);
            ac[mi] = MFMA16(A[mi][kk], BUF[8 + kk], ac[mi]);
        }
    }

    // reload BUF with t+1's fragments; L2 latency hides under activations
    if (T < 7) {
        const char* src = fW + (size_t)(T + 1) * 12288 + (size_t)l * 16;
#pragma unroll
        for (int i = 0; i < 12; ++i)
            BUF[i] = *reinterpret_cast<const bf16x8*>(src + (size_t)i * 1024);
    }

#pragma unroll
    for (int mi = 0; mi < 2; ++mi) {
#pragma unroll
        for (int r = 0; r < 4; ++r) {
            // logits already scaled: xi' = -log2e*xi, xc' = 2log2e*xc
            float ei = fexp2(ai[mi][r] + Bi);                 // e^-xi
            float eo = fexp2(ao[mi][r] + Bo);                 // e^-xo
            float xc = fminf(ac[mi][r] + Bc, 126.0f);
            float u  = fexp2(xc);                             // e^{2 xc}
            float cc = (u - 1.0f) * frcp((1.0f + ei) * (u + 1.0f));  // sig(i)*tanh(c~)
            float u2   = cc * cc;                             // Pade[5/4] tanh, |cc|<1
            float numx = cc * ((u2 + 105.0f) * u2 + 945.0f);
            float den  = ((15.0f * u2 + 420.0f) * u2 + 945.0f) * (1.0f + eo);
            float h    = numx * frcp(den);
            if (LAYER == 1) msum[T] += h;
            else hb[mi * 16 + g * 4 + r][c] = f2bf(h);
        }
    }
}

// ---------------------------------------------------------------------------
// Main fused kernel: 1024 blocks x 256 threads; each wave owns 32 rows.
// NO block-wide barriers until the final reduce.  VGPR pinned to 128 for
// 4 waves/SIMD (16 waves/CU; LDS 36.9KB -> 4 blocks/CU).
// ---------------------------------------------------------------------------
__global__ __launch_bounds__(256)
__attribute__((amdgpu_num_vgpr(128)))
void tree_enc(
        const float* __restrict__ X,       // [131072][64]
        const float* __restrict__ emb_b,   // [128]
        const char*  __restrict__ frags,   // ws
        float* __restrict__ out) {         // [256][128]

    __shared__ __align__(16) unsigned short hbuf[4][32][136];   // 34816 B
    __shared__ float redbuf[4][128];                            //  2048 B

    const int tid = threadIdx.x;
    const int w   = tid >> 6;
    const int l   = tid & 63;
    const int g   = l >> 4;
    const int c0  = l & 15;
    const int rowbase = blockIdx.x * 128 + w * 32;
    const int b  = blockIdx.x >> 2;       // 4 blocks per batch

    unsigned short (* __restrict__ hb)[136] = hbuf[w];
    const float* biasf = reinterpret_cast<const float*>(frags + 212992);

    // ---------------- embedding: h0 = X @ embW + emb_b ----------------
    {
        bf16x8 afr[2][2];
#pragma unroll
        for (int mi = 0; mi < 2; ++mi) {
#pragma unroll
            for (int kk = 0; kk < 2; ++kk) {
                int row = rowbase + mi * 16 + c0;
                const float4* p = reinterpret_cast<const float4*>(
                        X + (size_t)row * 64 + kk * 32 + g * 8);
                float4 v0 = p[0], v1 = p[1];
                bf16x8 a;
                a[0] = (short)f2bf(v0.x); a[1] = (short)f2bf(v0.y);
                a[2] = (short)f2bf(v0.z); a[3] = (short)f2bf(v0.w);
                a[4] = (short)f2bf(v1.x); a[5] = (short)f2bf(v1.y);
                a[6] = (short)f2bf(v1.z); a[7] = (short)f2bf(v1.w);
                afr[mi][kk] = a;
            }
        }
        const f32x4 z4 = {0.f, 0.f, 0.f, 0.f};
#pragma unroll
        for (int t = 0; t < 8; ++t) {
            f32x4 acc[2] = {z4, z4};
#pragma unroll
            for (int kk = 0; kk < 2; ++kk) {
                bf16x8 bf = *reinterpret_cast<const bf16x8*>(
                        frags + ((size_t)(t * 2 + kk) * 64 + l) * 16);
#pragma unroll
                for (int mi = 0; mi < 2; ++mi)
                    acc[mi] = MFMA16(afr[mi][kk], bf, acc[mi]);
            }
            float bias = emb_b[t * 16 + c0];
#pragma unroll
            for (int mi = 0; mi < 2; ++mi)
#pragma unroll
                for (int r = 0; r < 4; ++r)
                    hb[mi * 16 + g * 4 + r][t * 16 + c0] =
                        f2bf(acc[mi][r] + bias);   // C: col=l&15, row=4*(l>>4)+r
        }
    }

    // ---------------- 2 TreeLSTM layers (no barriers) ----------------
    float msum[8];
#pragma unroll
    for (int t = 0; t < 8; ++t) msum[t] = 0.f;

#define RUN_LAYER(L) do {                                                     \
        const char* fW = frags + 16384 + (size_t)(L) * 98304;                 \
        const float* bias = biasf + (L) * 384;                                \
        bf16x8 A[2][4];                                                       \
        _Pragma("unroll") for (int mi = 0; mi < 2; ++mi)                      \
        _Pragma("unroll") for (int kk = 0; kk < 4; ++kk)                      \
            A[mi][kk] = *reinterpret_cast<const bf16x8*>(                     \
                    &hb[mi * 16 + c0][kk * 32 + g * 8]);                      \
        bf16x8 buf[12];                                                       \
        { const char* s0 = fW + (size_t)l * 16;                               \
          _Pragma("unroll") for (int i = 0; i < 12; ++i)                      \
              buf[i] = *reinterpret_cast<const bf16x8*>(s0 + (size_t)i * 1024); } \
        t_step<0, L>(buf, A, fW, bias, l, c0, g, msum, hb);                   \
        t_step<1, L>(buf, A, fW, bias, l, c0, g, msum, hb);                   \
        t_step<2, L>(buf, A, fW, bias, l, c0, g, msum, hb);                   \
        t_step<3, L>(buf, A, fW, bias, l, c0, g, msum, hb);                   \
        t_step<4, L>(buf, A, fW, bias, l, c0, g, msum, hb);                   \
        t_step<5, L>(buf, A, fW, bias, l, c0, g, msum, hb);                   \
        t_step<6, L>(buf, A, fW, bias, l, c0, g, msum, hb);                   \
        t_step<7, L>(buf, A, fW, bias, l, c0, g, msum, hb);                   \
    } while (0)

    RUN_LAYER(0);
    RUN_LAYER(1);
#undef RUN_LAYER

    // ---------------- mean over nodes (single barrier) ----------------
#pragma unroll
    for (int t = 0; t < 8; ++t) {
        float v = msum[t];
        v += __shfl_xor(v, 16);
        v += __shfl_xor(v, 32);
        if (g == 0) redbuf[w][t * 16 + c0] = v;
    }
    __syncthreads();
    if (tid < 128) {
        float s = redbuf[0][tid] + redbuf[1][tid] + redbuf[2][tid] + redbuf[3][tid];
        atomicAdd(&out[b * 128 + tid], s * (1.0f / 512.0f));
    }
}

// ---------------------------------------------------------------------------
extern "C" void kernel_launch(void* const* d_in, const int* in_sizes, int n_in,
                              void* d_out, int out_size, void* d_ws, size_t ws_size,
                              hipStream_t stream) {
    const float* X    = (const float*)d_in[0];
    const float* embW = (const float*)d_in[1];
    const float* embb = (const float*)d_in[2];
    const float* Wi   = (const float*)d_in[3];
    const float* Wo   = (const float*)d_in[4];
    const float* Wc   = (const float*)d_in[5];
    const float* bWi  = (const float*)d_in[6];
    const float* bUi  = (const float*)d_in[7];
    const float* bWo  = (const float*)d_in[8];
    const float* bUo  = (const float*)d_in[9];
    const float* bWc  = (const float*)d_in[10];
    const float* bUc  = (const float*)d_in[11];
    float* out = (float*)d_out;
    char*  ws  = (char*)d_ws;

    hipMemsetAsync(d_out, 0, (size_t)out_size * sizeof(float), stream);
    prep_frags<<<209, 64, 0, stream>>>(embW, Wi, Wo, Wc,
                                       bWi, bUi, bWo, bUo, bWc, bUc, ws);
    tree_enc<<<1024, 256, 0, stream>>>(X, embb, (const char*)ws, out);
}

// Round 9
// 65.000 us; speedup vs baseline: 1.4669x; 1.0271x over previous
//
#include <hip/hip_runtime.h>

// ---------------------------------------------------------------------------
// TreeEncoder fused MFMA kernel, round 9.
//   r8 (59.4us kernel): 4 waves/SIMD, but every wave re-streams 208KB of
//   weight fragments from L2 => 852MB chip-wide ~= 22us of L2/L1 service.
//   Only the LDS pipe (256B/cy/CU) broadcasts cheaply. This round stages
//   fragments in LDS *without* giving up r8's occupancy:
//   - double-buffered 12KB/t staging, ONE barrier per t (dbuf lets a single
//     barrier fence both write-visibility and anti-dependence);
//   - hbuf (33KB) replaced by a wave-private 2.5KB kk-slab: h cols are born
//     32-at-a-time (t-pairs) -> write slab at t=2kk,2kk+1, read the A-frag
//     for kk at end of odd t, reuse. Wave-private DS is in-order: no sync.
//   - LDS 36.9KB -> 4 blocks/CU; VGPR capped 128 -> 16 waves/CU (r8-proven).
//   - unified 16-step loop (layer = step>>3); stage loads issued early.
//   Staged bytes are an exact copy of what r8's MFMAs read -> bit-identical.
// ---------------------------------------------------------------------------

typedef short bf16x8 __attribute__((ext_vector_type(8)));
typedef float f32x4  __attribute__((ext_vector_type(4)));

#define MFMA16(a, b, c) __builtin_amdgcn_mfma_f32_16x16x32_bf16((a), (b), (c), 0, 0, 0)

#define NEG_L2E (-1.44269504088896f)
#define TWO_L2E (2.88539008177793f)

__device__ __forceinline__ unsigned short f2bf(float f) {
    return (unsigned short)((__float_as_uint(f) + 0x8000u) >> 16);
}
__device__ __forceinline__ float frcp(float x)  { return __builtin_amdgcn_rcpf(x); }
__device__ __forceinline__ float fexp2(float x) { return __builtin_amdgcn_exp2f(x); }

// ---------------------------------------------------------------------------
// Prep: weights -> MFMA B-fragment bf16 layout in ws, with exp2 prescale;
// plus combined scaled biases.  (identical to round 8)
//   ws map (bytes):
//     [0, 16384)        emb_W: block = t*2 + kk          (unscaled)
//     [16384, 212992)   gates: block = (layer*8+t)*12 + gate*4 + kk
//         gate 0/1 (Wi,Wo): * -log2e    gate 2 (Wc): * 2*log2e
//     [212992, 216064)  biases: float[2][3][128], same scaling, bW+bU combined
// ---------------------------------------------------------------------------
__global__ void prep_frags(const float* __restrict__ embW,
                           const float* __restrict__ Wi,
                           const float* __restrict__ Wo,
                           const float* __restrict__ Wc,
                           const float* __restrict__ bWi, const float* __restrict__ bUi,
                           const float* __restrict__ bWo, const float* __restrict__ bUo,
                           const float* __restrict__ bWc, const float* __restrict__ bUc,
                           char* __restrict__ ws) {
    int fb = blockIdx.x;          // 0..208
    int l  = threadIdx.x;         // 0..63

    if (fb == 208) {              // combined scaled biases: [layer][gate][128]
        float* bias = reinterpret_cast<float*>(ws + 212992);
#pragma unroll
        for (int j = 0; j < 12; ++j) {
            int v = j * 64 + l;                 // 0..767
            int layer = v / 384;
            int r = v % 384;
            int gate = r >> 7;
            int c = r & 127;
            int idx = layer * 128 + c;
            float x;
            if (gate == 0)      x = NEG_L2E * (bWi[idx] + bUi[idx]);
            else if (gate == 1) x = NEG_L2E * (bWo[idx] + bUo[idx]);
            else                x = TWO_L2E * (bWc[idx] + bUc[idx]);
            bias[v] = x;
        }
        return;
    }

    int g  = l >> 4, c0 = l & 15;
    const float* src;
    int t, kk;
    size_t dst;
    float scale;
    if (fb < 16) {
        t = fb >> 1; kk = fb & 1;
        src = embW;                                   // [64][128]
        dst = (size_t)fb * 1024;
        scale = 1.0f;
    } else {
        int r = fb - 16;                              // (layer*8+t)*12+gate*4+kk
        int layer = r / 96;
        int r2 = r % 96;
        t = r2 / 12;
        int r3 = r2 % 12;
        int gate = r3 >> 2;
        kk = r3 & 3;
        const float* Ws[3] = {Wi, Wo, Wc};
        src = Ws[gate] + (size_t)layer * 128 * 128;   // [128][128]
        dst = 16384 + (size_t)r * 1024;
        scale = (gate == 2) ? TWO_L2E : NEG_L2E;
    }

    bf16x8 v;
#pragma unroll
    for (int e = 0; e < 8; ++e) {
        int k   = kk * 32 + g * 8 + e;
        int col = t * 16 + c0;
        v[e] = (short)f2bf(scale * src[(size_t)k * 128 + col]);
    }
    *reinterpret_cast<bf16x8*>(ws + dst + (size_t)l * 16) = v;
}

// ---------------------------------------------------------------------------
// One step of the unified 16-step loop.  STEP 0..15: layer = STEP>>3,
// T = STEP&7.  Per step: issue next-step stage loads -> MFMA from LDS ->
// stage-write next buffer -> activations -> (odd T, layer 0: A1 slab read)
// -> one barrier.
// ---------------------------------------------------------------------------
template<int STEP>
__device__ __forceinline__ void t_step(
        const char* __restrict__ frags,
        char* __restrict__ sb0, char* __restrict__ sb1,
        bf16x8 (&A0)[2][4], bf16x8 (&A1)[2][4],
        unsigned short* __restrict__ slab,     // wave-private [32][40]
        const float* __restrict__ biasf,
        float (&msum)[8],
        int tid, int l, int g, int c0) {

    constexpr int L = STEP >> 3;
    constexpr int T = STEP & 7;

    // issue-early: next step's 12KB stage loads (global -> regs)
    bf16x8 pre0, pre1, pre2;
    if constexpr (STEP < 15) {
        const char* s = frags + 16384 + (size_t)(STEP + 1) * 12288 + (size_t)tid * 16;
        pre0 = *reinterpret_cast<const bf16x8*>(s);
        pre1 = *reinterpret_cast<const bf16x8*>(s + 4096);
        pre2 = *reinterpret_cast<const bf16x8*>(s + 8192);
    }

    // -------- MFMA from staged LDS fragments --------
    const char* sr = ((STEP & 1) ? sb1 : sb0) + (size_t)l * 16;
    bf16x8 (&A)[2][4] = (L == 0) ? A0 : A1;
    const f32x4 z4 = {0.f, 0.f, 0.f, 0.f};
    f32x4 ai[2] = {z4, z4}, ao[2] = {z4, z4}, ac[2] = {z4, z4};
#pragma unroll
    for (int kk = 0; kk < 4; ++kk) {
        bf16x8 bi = *reinterpret_cast<const bf16x8*>(sr + (size_t)(0 + kk) * 1024);
        bf16x8 bo = *reinterpret_cast<const bf16x8*>(sr + (size_t)(4 + kk) * 1024);
        bf16x8 bc = *reinterpret_cast<const bf16x8*>(sr + (size_t)(8 + kk) * 1024);
#pragma unroll
        for (int mi = 0; mi < 2; ++mi) {
            ai[mi] = MFMA16(A[mi][kk], bi, ai[mi]);
            ao[mi] = MFMA16(A[mi][kk], bo, ao[mi]);
            ac[mi] = MFMA16(A[mi][kk], bc, ac[mi]);
        }
    }

    // -------- stage-write next buffer (vmcnt covered by MFMA section) ----
    if constexpr (STEP < 15) {
        char* d = ((STEP & 1) ? sb0 : sb1) + (size_t)tid * 16;
        *reinterpret_cast<bf16x8*>(d)        = pre0;
        *reinterpret_cast<bf16x8*>(d + 4096) = pre1;
        *reinterpret_cast<bf16x8*>(d + 8192) = pre2;
    }

    // -------- activations --------
    const int c = T * 16 + c0;
    const float Bi = biasf[L * 384 + c];
    const float Bo = biasf[L * 384 + 128 + c];
    const float Bc = biasf[L * 384 + 256 + c];
#pragma unroll
    for (int mi = 0; mi < 2; ++mi) {
#pragma unroll
        for (int r = 0; r < 4; ++r) {
            float ei = fexp2(ai[mi][r] + Bi);                 // e^-xi
            float eo = fexp2(ao[mi][r] + Bo);                 // e^-xo
            float u  = fexp2(ac[mi][r] + Bc);                 // e^{2 xc}; |arg|<=93
            float cc = (u - 1.0f) * frcp((1.0f + ei) * (u + 1.0f));
            float u2   = cc * cc;                             // Pade[5/4], |cc|<1
            float numx = cc * ((u2 + 105.0f) * u2 + 945.0f);
            float den  = ((15.0f * u2 + 420.0f) * u2 + 945.0f) * (1.0f + eo);
            float h    = numx * frcp(den);
            if constexpr (L == 1) {
                msum[T] += h;
            } else {
                slab[(mi * 16 + g * 4 + r) * 40 + (T & 1) * 16 + c0] = f2bf(h);
            }
        }
    }

    // -------- layer-0, odd T: slab now holds cols 32kk..32kk+31 -> A1 ----
    if constexpr (L == 0 && (T & 1) == 1) {
#pragma unroll
        for (int mi = 0; mi < 2; ++mi)
            A1[mi][T >> 1] = *reinterpret_cast<const bf16x8*>(
                    &slab[(mi * 16 + c0) * 40 + g * 8]);
    }

    __syncthreads();
}

// ---------------------------------------------------------------------------
// Main fused kernel: 1024 blocks x 256 threads; each wave owns 32 rows.
// One barrier per step (16) + prologue + reduce.
// ---------------------------------------------------------------------------
__global__ __launch_bounds__(256)
__attribute__((amdgpu_num_vgpr(128)))
void tree_enc(
        const float* __restrict__ X,       // [131072][64]
        const float* __restrict__ emb_b,   // [128]
        const char*  __restrict__ frags,   // ws
        float* __restrict__ out) {         // [256][128]

    __shared__ __align__(16) char sbuf[2][12288];               // 24576 B
    __shared__ __align__(16) unsigned short slabs[4][32 * 40];  // 10240 B
    __shared__ float redbuf[4][128];                            //  2048 B

    const int tid = threadIdx.x;
    const int w   = tid >> 6;
    const int l   = tid & 63;
    const int g   = l >> 4;
    const int c0  = l & 15;
    const int rowbase = blockIdx.x * 128 + w * 32;
    const int b  = blockIdx.x >> 2;       // 4 blocks per batch

    unsigned short* __restrict__ slab = slabs[w];
    const float* biasf = reinterpret_cast<const float*>(frags + 212992);

    // prologue: issue step-0 stage loads now; write after embedding
    bf16x8 p0, p1, p2;
    {
        const char* s = frags + 16384 + (size_t)tid * 16;
        p0 = *reinterpret_cast<const bf16x8*>(s);
        p1 = *reinterpret_cast<const bf16x8*>(s + 4096);
        p2 = *reinterpret_cast<const bf16x8*>(s + 8192);
    }

    // ---------------- embedding: h0 = X @ embW + emb_b -> A0 via slab ----
    bf16x8 A0[2][4], A1[2][4];
    {
        bf16x8 afr[2][2];
#pragma unroll
        for (int mi = 0; mi < 2; ++mi) {
#pragma unroll
            for (int kk = 0; kk < 2; ++kk) {
                int row = rowbase + mi * 16 + c0;
                const float4* p = reinterpret_cast<const float4*>(
                        X + (size_t)row * 64 + kk * 32 + g * 8);
                float4 v0 = p[0], v1 = p[1];
                bf16x8 a;
                a[0] = (short)f2bf(v0.x); a[1] = (short)f2bf(v0.y);
                a[2] = (short)f2bf(v0.z); a[3] = (short)f2bf(v0.w);
                a[4] = (short)f2bf(v1.x); a[5] = (short)f2bf(v1.y);
                a[6] = (short)f2bf(v1.z); a[7] = (short)f2bf(v1.w);
                afr[mi][kk] = a;
            }
        }
        const f32x4 z4 = {0.f, 0.f, 0.f, 0.f};
#pragma unroll
        for (int t = 0; t < 8; ++t) {
            f32x4 acc[2] = {z4, z4};
#pragma unroll
            for (int kk = 0; kk < 2; ++kk) {
                bf16x8 bf = *reinterpret_cast<const bf16x8*>(
                        frags + ((size_t)(t * 2 + kk) * 64 + l) * 16);
#pragma unroll
                for (int mi = 0; mi < 2; ++mi)
                    acc[mi] = MFMA16(afr[mi][kk], bf, acc[mi]);
            }
            float bias = emb_b[t * 16 + c0];
#pragma unroll
            for (int mi = 0; mi < 2; ++mi)
#pragma unroll
                for (int r = 0; r < 4; ++r)
                    slab[(mi * 16 + g * 4 + r) * 40 + (t & 1) * 16 + c0] =
                        f2bf(acc[mi][r] + bias);   // C: col=l&15, row=4*(l>>4)+r
            if (t & 1) {
#pragma unroll
                for (int mi = 0; mi < 2; ++mi)
                    A0[mi][t >> 1] = *reinterpret_cast<const bf16x8*>(
                            &slab[(mi * 16 + c0) * 40 + g * 8]);
            }
        }
    }

    // stage step-0 fragments (loads issued before embedding)
    {
        char* d = sbuf[0] + (size_t)tid * 16;
        *reinterpret_cast<bf16x8*>(d)        = p0;
        *reinterpret_cast<bf16x8*>(d + 4096) = p1;
        *reinterpret_cast<bf16x8*>(d + 8192) = p2;
    }
    __syncthreads();

    // ---------------- 16 steps: layer 0 (A0 -> A1), layer 1 (A1) ---------
    float msum[8];
#pragma unroll
    for (int t = 0; t < 8; ++t) msum[t] = 0.f;

    char* sb0 = sbuf[0];
    char* sb1 = sbuf[1];
    t_step< 0>(frags, sb0, sb1, A0, A1, slab, biasf, msum, tid, l, g, c0);
    t_step< 1>(frags, sb0, sb1, A0, A1, slab, biasf, msum, tid, l, g, c0);
    t_step< 2>(frags, sb0, sb1, A0, A1, slab, biasf, msum, tid, l, g, c0);
    t_step< 3>(frags, sb0, sb1, A0, A1, slab, biasf, msum, tid, l, g, c0);
    t_step< 4>(frags, sb0, sb1, A0, A1, slab, biasf, msum, tid, l, g, c0);
    t_step< 5>(frags, sb0, sb1, A0, A1, slab, biasf, msum, tid, l, g, c0);
    t_step< 6>(frags, sb0, sb1, A0, A1, slab, biasf, msum, tid, l, g, c0);
    t_step< 7>(frags, sb0, sb1, A0, A1, slab, biasf, msum, tid, l, g, c0);
    t_step< 8>(frags, sb0, sb1, A0, A1, slab, biasf, msum, tid, l, g, c0);
    t_step< 9>(frags, sb0, sb1, A0, A1, slab, biasf, msum, tid, l, g, c0);
    t_step<10>(frags, sb0, sb1, A0, A1, slab, biasf, msum, tid, l, g, c0);
    t_step<11>(frags, sb0, sb1, A0, A1, slab, biasf, msum, tid, l, g, c0);
    t_step<12>(frags, sb0, sb1, A0, A1, slab, biasf, msum, tid, l, g, c0);
    t_step<13>(frags, sb0, sb1, A0, A1, slab, biasf, msum, tid, l, g, c0);
    t_step<14>(frags, sb0, sb1, A0, A1, slab, biasf, msum, tid, l, g, c0);
    t_step<15>(frags, sb0, sb1, A0, A1, slab, biasf, msum, tid, l, g, c0);

    // ---------------- mean over nodes ----------------
#pragma unroll
    for (int t = 0; t < 8; ++t) {
        float v = msum[t];
        v += __shfl_xor(v, 16);
        v += __shfl_xor(v, 32);
        if (g == 0) redbuf[w][t * 16 + c0] = v;
    }
    __syncthreads();
    if (tid < 128) {
        float s = redbuf[0][tid] + redbuf[1][tid] + redbuf[2][tid] + redbuf[3][tid];
        atomicAdd(&out[b * 128 + tid], s * (1.0f / 512.0f));
    }
}

// ---------------------------------------------------------------------------
extern "C" void kernel_launch(void* const* d_in, const int* in_sizes, int n_in,
                              void* d_out, int out_size, void* d_ws, size_t ws_size,
                              hipStream_t stream) {
    const float* X    = (const float*)d_in[0];
    const float* embW = (const float*)d_in[1];
    const float* embb = (const float*)d_in[2];
    const float* Wi   = (const float*)d_in[3];
    const float* Wo   = (const float*)d_in[4];
    const float* Wc   = (const float*)d_in[5];
    const float* bWi  = (const float*)d_in[6];
    const float* bUi  = (const float*)d_in[7];
    const float* bWo  = (const float*)d_in[8];
    const float* bUo  = (const float*)d_in[9];
    const float* bWc  = (const float*)d_in[10];
    const float* bUc  = (const float*)d_in[11];
    float* out = (float*)d_out;
    char*  ws  = (char*)d_ws;

    hipMemsetAsync(d_out, 0, (size_t)out_size * sizeof(float), stream);
    prep_frags<<<209, 64, 0, stream>>>(embW, Wi, Wo, Wc,
                                       bWi, bUi, bWo, bUo, bWc, bUc, ws);
    tree_enc<<<1024, 256, 0, stream>>>(X, embb, (const char*)ws, out);
}